// Round 1
// baseline (125.203 us; speedup 1.0000x reference)
//
#include <hip/hip_runtime.h>

// S4D kernel materialization:
//   dt   = exp(log_dt[h])
//   A    = -exp(log_A_real) + i*A_imag
//   dtA  = A*dt ; w = exp(dtA)
//   Cc   = C * (w - 1) / A
//   K[h,l] = 2 * Re( sum_n Cc[h,n] * w[h,n]^l )
//
// Strategy: geometric recurrence. Block per h; thread t owns l = t + 256*j.
// State s[n] = 2*Cc[n]*w^t (complex), step multiplier W = w^256 (block-uniform,
// hoisted to SGPRs). Inner loop = 5 VALU ops per (mode, sample), zero
// transcendentals.

static __device__ __forceinline__ float bcast0(float x) {
    return __uint_as_float(__builtin_amdgcn_readfirstlane(__float_as_uint(x)));
}

template <int N2, int BLK>
__global__ __launch_bounds__(BLK, 4) void s4d_kernel(
    const float* __restrict__ C,
    const float* __restrict__ log_dt,
    const float* __restrict__ log_A_real,
    const float* __restrict__ A_imag,
    float* __restrict__ K,
    int L, int J)
{
    __shared__ float s_dre[N2], s_dim[N2];   // dtA (re, im)
    __shared__ float s_Wre[N2], s_Wim[N2];   // W = w^BLK
    __shared__ float s_cre[N2], s_cim[N2];   // 2*Cc

    const int h = blockIdx.x;
    const int t = threadIdx.x;

    if (t < N2) {
        const int n = t;
        const float dt  = expf(log_dt[h]);
        const float Are = -expf(log_A_real[h * N2 + n]);
        const float Aim = A_imag[h * N2 + n];
        const float dre = Are * dt;
        const float dim = Aim * dt;
        // w = exp(dtA)
        float sw, cw;
        sincosf(dim, &sw, &cw);
        const float er  = expf(dre);
        const float wre = er * cw;
        const float wim = er * sw;
        // (w - 1) / A  (complex divide by A = Are + i*Aim)
        const float nre = wre - 1.0f;
        const float nim = wim;
        const float inv = 1.0f / (Are * Are + Aim * Aim);
        const float qre = (nre * Are + nim * Aim) * inv;
        const float qim = (nim * Are - nre * Aim) * inv;
        const float c2  = 2.0f * C[h * N2 + n];
        s_cre[n] = c2 * qre;
        s_cim[n] = c2 * qim;
        s_dre[n] = dre;
        s_dim[n] = dim;
        // W = w^BLK = exp(dtA * BLK)
        const float TB = (float)BLK;
        float sT, cT;
        sincosf(dim * TB, &sT, &cT);
        const float erT = expf(dre * TB);
        s_Wre[n] = erT * cT;
        s_Wim[n] = erT * sT;
    }
    __syncthreads();

    // Per-thread state init: s[n] = 2*Cc[n] * w^t  (exact via exp/sincos, t<=255)
    float sre[N2], sim[N2];
    float Wre[N2], Wim[N2];
    const float tf = (float)t;
#pragma unroll
    for (int n = 0; n < N2; ++n) {
        const float dre = s_dre[n];
        const float dim = s_dim[n];
        const float m = expf(dre * tf);
        float ss, cc;
        sincosf(dim * tf, &ss, &cc);
        const float pre = m * cc;
        const float pim = m * ss;
        const float cre = s_cre[n];
        const float cim = s_cim[n];
        sre[n] = cre * pre - cim * pim;
        sim[n] = cre * pim + cim * pre;
        // Block-uniform step multiplier -> SGPRs (saves 64 VGPRs)
        Wre[n] = bcast0(s_Wre[n]);
        Wim[n] = bcast0(s_Wim[n]);
    }

    float* __restrict__ outp = K + (size_t)h * (size_t)L + t;
    for (int j = 0; j < J; ++j) {
        float acc = 0.0f;
#pragma unroll
        for (int n = 0; n < N2; ++n) acc += sre[n];
        if (j + 1 < J) {  // uniform branch: skip dead final update
#pragma unroll
            for (int n = 0; n < N2; ++n) {
                const float tr = fmaf(sre[n], Wre[n], -(sim[n] * Wim[n]));
                sim[n] = fmaf(sre[n], Wim[n], sim[n] * Wre[n]);
                sre[n] = tr;
            }
        }
        const int l = j * BLK + t;
        if (l < L) outp[(size_t)j * BLK] = acc;
    }
}

extern "C" void kernel_launch(void* const* d_in, const int* in_sizes, int n_in,
                              void* d_out, int out_size, void* d_ws, size_t ws_size,
                              hipStream_t stream)
{
    const float* C          = (const float*)d_in[0];
    const float* log_dt     = (const float*)d_in[1];
    const float* log_A_real = (const float*)d_in[2];
    const float* A_imag     = (const float*)d_in[3];
    float* K = (float*)d_out;

    const int H  = in_sizes[1];           // 1024
    const int N2 = in_sizes[0] / H;       // 32
    const int L  = out_size / H;          // 4096
    constexpr int BLK = 256;
    const int J = (L + BLK - 1) / BLK;    // 16

    if (N2 == 32) {
        s4d_kernel<32, BLK><<<H, BLK, 0, stream>>>(C, log_dt, log_A_real, A_imag, K, L, J);
    }
}

// Round 2
// 93.479 us; speedup vs baseline: 1.3394x; 1.3394x over previous
//
#include <hip/hip_runtime.h>

// S4D kernel materialization:
//   dt   = exp(log_dt[h]) ; A = -exp(log_A_real) + i*A_imag
//   dtA  = A*dt ; w = exp(dtA) ; Cc = C * (w - 1) / A
//   K[h,l] = 2 * Re( sum_n Cc[h,n] * w[h,n]^l )
//
// R1 lesson: modes-outer loop order. Persistent per-thread state is only
// acc[J] (16 VGPRs, statically indexed). Per mode: init s = 2*Cc*w^(lbase+t)
// exactly via exp/sincos, then J steps of {acc[j] += Re(s); s *= W} where
// W = w^BLK is block-uniform (SGPR via readfirstlane). No spill.

static __device__ __forceinline__ float bcast0(float x) {
    return __uint_as_float(__builtin_amdgcn_readfirstlane(__float_as_uint(x)));
}

template <int N2, int BLK, int J>
__global__ __launch_bounds__(BLK, 4) void s4d_kernel(
    const float* __restrict__ C,
    const float* __restrict__ log_dt,
    const float* __restrict__ log_A_real,
    const float* __restrict__ A_imag,
    float* __restrict__ K,
    int L, int lbase)
{
    __shared__ float s_dre[N2], s_dim[N2];   // dtA (re, im)
    __shared__ float s_Wre[N2], s_Wim[N2];   // W = w^BLK
    __shared__ float s_cre[N2], s_cim[N2];   // 2*Cc

    const int h = blockIdx.x;
    const int t = threadIdx.x;

    if (t < N2) {
        const int n = t;
        const float dt  = expf(log_dt[h]);
        const float Are = -expf(log_A_real[h * N2 + n]);
        const float Aim = A_imag[h * N2 + n];
        const float dre = Are * dt;
        const float dim = Aim * dt;
        // w = exp(dtA)
        float sw, cw;
        sincosf(dim, &sw, &cw);
        const float er  = expf(dre);
        const float wre = er * cw;
        const float wim = er * sw;
        // (w - 1) / A
        const float nre = wre - 1.0f;
        const float nim = wim;
        const float inv = 1.0f / (Are * Are + Aim * Aim);
        const float qre = (nre * Are + nim * Aim) * inv;
        const float qim = (nim * Are - nre * Aim) * inv;
        const float c2  = 2.0f * C[h * N2 + n];
        s_cre[n] = c2 * qre;
        s_cim[n] = c2 * qim;
        s_dre[n] = dre;
        s_dim[n] = dim;
        // W = w^BLK
        const float TB = (float)BLK;
        float sT, cT;
        sincosf(dim * TB, &sT, &cT);
        const float erT = expf(dre * TB);
        s_Wre[n] = erT * cT;
        s_Wim[n] = erT * sT;
    }
    __syncthreads();

    float acc[J];
#pragma unroll
    for (int j = 0; j < J; ++j) acc[j] = 0.0f;

    const float l0 = (float)(lbase + t);

    for (int n = 0; n < N2; ++n) {
        const float dre = s_dre[n];
        const float dim = s_dim[n];
        const float cre = s_cre[n];
        const float cim = s_cim[n];
        const float Wre = bcast0(s_Wre[n]);
        const float Wim = bcast0(s_Wim[n]);

        // s = 2*Cc * w^l0 (exact init; sincosf handles large args)
        const float m = expf(dre * l0);
        float ss, cc;
        sincosf(dim * l0, &ss, &cc);
        const float pre = m * cc;
        const float pim = m * ss;
        float sre = cre * pre - cim * pim;
        float smi = cre * pim + cim * pre;

#pragma unroll
        for (int j = 0; j < J - 1; ++j) {
            acc[j] += sre;
            const float tr = fmaf(sre, Wre, -(smi * Wim));
            smi = fmaf(sre, Wim, smi * Wre);
            sre = tr;
        }
        acc[J - 1] += sre;   // final step: no dead multiply
    }

    float* __restrict__ outp = K + (size_t)h * (size_t)L + lbase + t;
#pragma unroll
    for (int j = 0; j < J; ++j) {
        const int l = lbase + j * BLK + t;
        if (l < L) outp[(size_t)j * BLK] = acc[j];
    }
}

extern "C" void kernel_launch(void* const* d_in, const int* in_sizes, int n_in,
                              void* d_out, int out_size, void* d_ws, size_t ws_size,
                              hipStream_t stream)
{
    const float* C          = (const float*)d_in[0];
    const float* log_dt     = (const float*)d_in[1];
    const float* log_A_real = (const float*)d_in[2];
    const float* A_imag     = (const float*)d_in[3];
    float* K = (float*)d_out;

    const int H  = in_sizes[1];           // 1024
    const int N2 = in_sizes[0] / H;       // 32
    const int L  = out_size / H;          // 4096
    constexpr int BLK = 256;
    constexpr int J   = 16;               // samples per thread per launch

    if (N2 != 32) return;
    // One launch covers BLK*J = 4096 samples of L; loop for larger L.
    for (int lbase = 0; lbase < L; lbase += BLK * J) {
        s4d_kernel<32, BLK, J><<<H, BLK, 0, stream>>>(
            C, log_dt, log_A_real, A_imag, K, L, lbase);
    }
}

// Round 3
// 84.494 us; speedup vs baseline: 1.4818x; 1.1063x over previous
//
#include <hip/hip_runtime.h>

// S4D kernel materialization:
//   dt = exp(log_dt[h]) ; A = -exp(log_A_real) + i*A_imag
//   dtA = A*dt ; w = exp(dtA) ; Cc = C*(w-1)/A
//   K[h,l] = 2 * Re( sum_n Cc[h,n] * w[h,n]^l )
//
// R2 lesson: per-thread sincosf at args up to ~2.5k rad hits the Payne-Hanek
// slow path and dominates. Replace ALL per-thread transcendentals with a
// two-level LDS power table built by complex-mul chains in setup:
//   s_lo[n][k] = 2*Cc*w^k   (k<16)
//   s_hi[n][k] = (w^16)^k   (k<16)
//   W          = w^256      (block-uniform -> SGPR)
// Thread t (sample l = t + 256j): s = s_lo[n][t&15]*s_hi[n][t>>4], then
// 15 recurrence steps {acc[j] += Re(s); s *= W}. 5 VALU/step, no trig.

static __device__ __forceinline__ float bcast0(float x) {
    return __uint_as_float(__builtin_amdgcn_readfirstlane(__float_as_uint(x)));
}

static __device__ __forceinline__ float2 cmul(float2 a, float2 b) {
    return make_float2(fmaf(a.x, b.x, -(a.y * b.y)),
                       fmaf(a.x, b.y,   a.y * b.x));
}

template <int N2, int BLK, int J>
__global__ __launch_bounds__(BLK, 4) void s4d_kernel(
    const float* __restrict__ C,
    const float* __restrict__ log_dt,
    const float* __restrict__ log_A_real,
    const float* __restrict__ A_imag,
    float* __restrict__ K,
    int L, int lbase)
{
    __shared__ float2 s_lo[N2][16];   // 2*Cc * w^k
    __shared__ float2 s_hi[N2][16];   // (w^16)^k
    __shared__ float2 s_W[N2];        // w^BLK

    const int h = blockIdx.x;
    const int t = threadIdx.x;

    if (t < N2) {
        const int n = t;
        const float dt  = expf(log_dt[h]);
        const float Are = -expf(log_A_real[h * N2 + n]);
        const float Aim = A_imag[h * N2 + n];
        const float dre = Are * dt;
        const float dim = Aim * dt;          // |dim| <= pi*31*0.1 ~ 9.7 rad (fast path)
        // w = exp(dtA)
        float sw, cw;
        sincosf(dim, &sw, &cw);
        const float er = expf(dre);
        const float2 w = make_float2(er * cw, er * sw);
        // 2*Cc = 2*C*(w-1)/A
        const float nre = w.x - 1.0f;
        const float nim = w.y;
        const float inv = 1.0f / (Are * Are + Aim * Aim);
        const float qre = (nre * Are + nim * Aim) * inv;
        const float qim = (nim * Are - nre * Aim) * inv;
        const float c2  = 2.0f * C[h * N2 + n];
        float2 cur = make_float2(c2 * qre, c2 * qim);   // 2*Cc * w^0
#pragma unroll
        for (int k = 0; k < 16; ++k) { s_lo[n][k] = cur; cur = cmul(cur, w); }
        // w^16 by squaring
        const float2 w2  = cmul(w,  w);
        const float2 w4  = cmul(w2, w2);
        const float2 w8  = cmul(w4, w4);
        const float2 w16 = cmul(w8, w8);
        float2 curh = make_float2(1.0f, 0.0f);
#pragma unroll
        for (int k = 0; k < 16; ++k) { s_hi[n][k] = curh; curh = cmul(curh, w16); }
        s_W[n] = curh;                                  // w^256 == w^BLK
    }
    __syncthreads();

    float acc[J];
#pragma unroll
    for (int j = 0; j < J; ++j) acc[j] = 0.0f;

    const int tlo = t & 15;
    const int thi = t >> 4;

#pragma unroll 4
    for (int n = 0; n < N2; ++n) {
        const float2 lo = s_lo[n][tlo];
        const float2 hi = s_hi[n][thi];
        const float Wre = bcast0(s_W[n].x);
        const float Wim = bcast0(s_W[n].y);

        float sre = fmaf(lo.x, hi.x, -(lo.y * hi.y));
        float smi = fmaf(lo.x, hi.y,   lo.y * hi.x);

#pragma unroll
        for (int j = 0; j < J - 1; ++j) {
            acc[j] += sre;
            const float tr = fmaf(sre, Wre, -(smi * Wim));
            smi = fmaf(sre, Wim, smi * Wre);
            sre = tr;
        }
        acc[J - 1] += sre;
    }

    float* __restrict__ outp = K + (size_t)h * (size_t)L + lbase + t;
#pragma unroll
    for (int j = 0; j < J; ++j) {
        const int l = lbase + j * BLK + t;
        if (l < L) outp[(size_t)j * BLK] = acc[j];
    }
}

extern "C" void kernel_launch(void* const* d_in, const int* in_sizes, int n_in,
                              void* d_out, int out_size, void* d_ws, size_t ws_size,
                              hipStream_t stream)
{
    const float* C          = (const float*)d_in[0];
    const float* log_dt     = (const float*)d_in[1];
    const float* log_A_real = (const float*)d_in[2];
    const float* A_imag     = (const float*)d_in[3];
    float* K = (float*)d_out;

    const int H  = in_sizes[1];           // 1024
    const int N2 = in_sizes[0] / H;       // 32
    const int L  = out_size / H;          // 4096
    constexpr int BLK = 256;
    constexpr int J   = 16;               // samples per thread per launch

    if (N2 != 32) return;
    for (int lbase = 0; lbase < L; lbase += BLK * J) {
        s4d_kernel<32, BLK, J><<<H, BLK, 0, stream>>>(
            C, log_dt, log_A_real, A_imag, K, L, lbase);
    }
}

// Round 5
// 81.123 us; speedup vs baseline: 1.5434x; 1.0416x over previous
//
#include <hip/hip_runtime.h>

// S4D kernel materialization:
//   dt = exp(log_dt[h]) ; A = -exp(log_A_real) + i*A_imag
//   dtA = A*dt ; w = exp(dtA) ; Cc = C*(w-1)/A
//   K[h,l] = 2 * Re( sum_n Cc[h,n] * w[h,n]^l )
//
// R3 lesson: stall-bound at 16/32 waves/CU, not issue-bound. R4:
//  (1) Chebyshev real recurrence x_{j+1} = 2Re(W) x_j - |W|^2 x_{j-1}
//      (exact for x_j = Re(s0*W^j)): 3 VALU per mode-sample, and the init
//      needs only real parts (lo/lo2 tables), no complex muls in main loop.
//  (2) J=8, grid (H, 2), __launch_bounds__(256,8): 8 blocks/CU = 32 waves/CU
//      (100% occupancy) for stall coverage. w^lbase folds into the tables.

static __device__ __forceinline__ float bcast0(float x) {
    return __uint_as_float(__builtin_amdgcn_readfirstlane(__float_as_uint(x)));
}

static __device__ __forceinline__ float2 cmul(float2 a, float2 b) {
    return make_float2(fmaf(a.x, b.x, -(a.y * b.y)),
                       fmaf(a.x, b.y,   a.y * b.x));
}

template <int N2, int BLK, int J>
__global__ __launch_bounds__(BLK, 8) void s4d_kernel(
    const float* __restrict__ C,
    const float* __restrict__ log_dt,
    const float* __restrict__ log_A_real,
    const float* __restrict__ A_imag,
    float* __restrict__ K,
    int L)
{
    __shared__ float2 s_lo [N2][16];  // 2*Cc * w^(lbase+k),          k<16
    __shared__ float2 s_lo2[N2][16];  // 2*Cc * w^(lbase+k) * W,      W = w^BLK
    __shared__ float2 s_hi [N2][16];  // (w^16)^k
    __shared__ float2 s_ab [N2];      // (2*Re(W), -|W|^2)

    const int h = blockIdx.x;
    const int y = blockIdx.y;
    const int lbase = y * (BLK * J);
    const int t = threadIdx.x;

    if (t < N2) {
        const int n = t;
        const float dt  = expf(log_dt[h]);
        const float Are = -expf(log_A_real[h * N2 + n]);
        const float Aim = A_imag[h * N2 + n];
        const float dre = Are * dt;
        const float dim = Aim * dt;           // |dim| <= ~9.7 rad: fast path
        float sw, cw;
        sincosf(dim, &sw, &cw);
        const float er = expf(dre);
        const float2 w = make_float2(er * cw, er * sw);
        // 2*Cc = 2*C*(w-1)/A
        const float nre = w.x - 1.0f;
        const float nim = w.y;
        const float inv = 1.0f / (Are * Are + Aim * Aim);
        const float qre = (nre * Are + nim * Aim) * inv;
        const float qim = (nim * Are - nre * Aim) * inv;
        const float c2  = 2.0f * C[h * N2 + n];
        // powers of w
        const float2 w2  = cmul(w,  w);
        const float2 w4  = cmul(w2, w2);
        const float2 w8  = cmul(w4, w4);
        const float2 w16 = cmul(w8, w8);
        float2 curh = make_float2(1.0f, 0.0f);
#pragma unroll
        for (int k = 0; k < 16; ++k) { s_hi[n][k] = curh; curh = cmul(curh, w16); }
        const float2 W = curh;                // w^BLK (BLK=256)
        s_ab[n] = make_float2(W.x + W.x, -fmaf(W.x, W.x, W.y * W.y));
        // w^lbase = W^(J*y) by binary pow (block-uniform small loop)
        float2 P = make_float2(1.0f, 0.0f);
        float2 base = W;
        int e = J * y;
        while (e) { if (e & 1) P = cmul(P, base); base = cmul(base, base); e >>= 1; }
        float2 cur  = cmul(make_float2(c2 * qre, c2 * qim), P);  // 2Cc * w^lbase
        float2 cur2 = cmul(cur, W);
#pragma unroll
        for (int k = 0; k < 16; ++k) {
            s_lo [n][k] = cur;  cur  = cmul(cur,  w);
            s_lo2[n][k] = cur2; cur2 = cmul(cur2, w);
        }
    }
    __syncthreads();

    float acc[J];
#pragma unroll
    for (int j = 0; j < J; ++j) acc[j] = 0.0f;

    const int tlo = t & 15;
    const int thi = t >> 4;

#pragma unroll 2
    for (int n = 0; n < N2; ++n) {
        const float2 lo  = s_lo [n][tlo];
        const float2 lo2 = s_lo2[n][tlo];
        const float2 hi  = s_hi [n][thi];
        const float  aW  = bcast0(s_ab[n].x);
        const float  bW  = bcast0(s_ab[n].y);

        float x0 = fmaf(lo.x,  hi.x, -(lo.y  * hi.y));   // Re(2Cc w^(lbase+t))
        float x1 = fmaf(lo2.x, hi.x, -(lo2.y * hi.y));   // Re(... * W)
        acc[0] += x0;
        acc[1] += x1;
#pragma unroll
        for (int j = 2; j < J; ++j) {
            const float x2 = fmaf(aW, x1, bW * x0);      // 2Re(W)x1 - |W|^2 x0
            acc[j] += x2;
            x0 = x1;
            x1 = x2;
        }
    }

    float* __restrict__ outp = K + (size_t)h * (size_t)L + lbase + t;
#pragma unroll
    for (int j = 0; j < J; ++j) {
        const int l = lbase + j * BLK + t;
        if (l < L) outp[(size_t)j * BLK] = acc[j];
    }
}

extern "C" void kernel_launch(void* const* d_in, const int* in_sizes, int n_in,
                              void* d_out, int out_size, void* d_ws, size_t ws_size,
                              hipStream_t stream)
{
    const float* C          = (const float*)d_in[0];
    const float* log_dt     = (const float*)d_in[1];
    const float* log_A_real = (const float*)d_in[2];
    const float* A_imag     = (const float*)d_in[3];
    float* K = (float*)d_out;

    const int H   = in_sizes[1];           // 1024
    const int N2v = in_sizes[0] / H;       // 32
    const int L   = out_size / H;          // 4096
    constexpr int BLK = 256;
    constexpr int J   = 8;                 // samples per thread
    const int gy = (L + BLK * J - 1) / (BLK * J);

    if (N2v != 32) return;
    dim3 grid((unsigned)H, (unsigned)gy);
    s4d_kernel<32, BLK, J><<<grid, BLK, 0, stream>>>(
        C, log_dt, log_A_real, A_imag, K, L);
}